// Round 12
// baseline (106.209 us; speedup 1.0000x reference)
//
#include <hip/hip_runtime.h>
#include <hip/hip_bf16.h>
#include <cstdint>

// Problem constants
#define Bn 8
#define Cn 64
#define Hn 112
#define Wn 112
#define On 64
#define Ln (Hn * Wn)   // 12544
#define HP 114
#define WP 114

typedef __attribute__((ext_vector_type(4)))  float f32x4;
typedef __attribute__((ext_vector_type(8)))  short bf16x8;
typedef __attribute__((ext_vector_type(4)))  unsigned int u32x4;

typedef __attribute__((address_space(3))) unsigned int lds_u32;
typedef __attribute__((address_space(1))) const unsigned int glob_u32;

__device__ __forceinline__ unsigned f2bf(float f) {
    unsigned u = __float_as_uint(f);
    unsigned r = 0x7fffu + ((u >> 16) & 1u);
    return (u + r) >> 16;   // RNE bf16 in low 16 bits
}

// -----------------------------------------------------------------------------
// Kernel 1 (fused prep):
//  blocks [0,912): x [B][C][112][112] f32 -> xps padded NHWC bf16 with the
//    LDS slot-permutation PRE-APPLIED: 16B chunk addr =
//      ((b*114 + row)*114 + wp)*8 + (c8 ^ (wp & 7)).
//    R1-style: one thread per padded col; reads lane-coalesced per channel
//    (512B/wave), writes 128B contiguous per thread (slots permuted inside).
//  blocks [912,948): weight -> wpk bf16 A-fragments for mfma_f32_16x16x32_bf16
//    (R1-verified layout): fidx = p*8 + of*2 + ki; per lane:
//    o = of*16 + (lane&15), c = ki*32 + (lane>>4)*8 + j  (j=0..7).
// -----------------------------------------------------------------------------
__global__ __launch_bounds__(128) void prep_kernel(const float* __restrict__ x,
                                                   const float* __restrict__ w,
                                                   unsigned short* __restrict__ xps,
                                                   unsigned short* __restrict__ wpk) {
    int blk = blockIdx.x;
    int t = threadIdx.x;
    if (blk < 912) {
        int b = blk / HP, hp = blk - b * HP;    // padded row
        int wp = t;
        if (wp >= WP) return;
        int h = hp - 1, wc = wp - 1;
        bool inb = ((unsigned)h < (unsigned)Hn) & ((unsigned)wc < (unsigned)Wn);
        const float* src = x + (size_t)b * Cn * Hn * Wn + (inb ? (h * Wn + wc) : 0);
        unsigned buf[32];
#pragma unroll
        for (int c = 0; c < Cn; c += 2) {
            float v0 = src[(size_t)c * (Hn * Wn)];
            float v1 = src[(size_t)(c + 1) * (Hn * Wn)];
            if (!inb) { v0 = 0.f; v1 = 0.f; }
            buf[c >> 1] = f2bf(v0) | (f2bf(v1) << 16);
        }
        unsigned short* dst = xps + ((size_t)(b * HP + hp) * WP + wp) * Cn;
        int sw = wp & 7;
#pragma unroll
        for (int i = 0; i < 8; ++i) {           // chunk c8=i -> slot i^sw
            u32x4 v;
            v[0] = buf[i * 4 + 0]; v[1] = buf[i * 4 + 1];
            v[2] = buf[i * 4 + 2]; v[3] = buf[i * 4 + 3];
            *reinterpret_cast<u32x4*>(dst + (size_t)(i ^ sw) * 8) = v;
        }
    } else {
        int idx = (blk - 912) * 2 + (t >> 6);   // 0..71 = p*8 + of*2 + ki
        int lane = t & 63;
        int ki = idx & 1, of = (idx >> 1) & 3, p = idx >> 3;
        int o  = of * 16 + (lane & 15);
        int cb = ki * 32 + (lane >> 4) * 8;
        unsigned pk[4];
#pragma unroll
        for (int j = 0; j < 4; ++j) {
            float v0 = w[((size_t)o * Cn + cb + 2 * j) * 9 + p];
            float v1 = w[((size_t)o * Cn + cb + 2 * j + 1) * 9 + p];
            pk[j] = f2bf(v0) | (f2bf(v1) << 16);
        }
        u32x4 v; v[0] = pk[0]; v[1] = pk[1]; v[2] = pk[2]; v[3] = pk[3];
        reinterpret_cast<u32x4*>(wpk)[idx * 64 + lane] = v;
    }
}

// -----------------------------------------------------------------------------
// Kernel 2: implicit-GEMM conv, 16x16x32 MFMA (R1-verified layout), per-pixel
// tap mask. OCCUPANCY-FIRST: block = 448 thr (7 waves), owns ONE output row
// (7 x 16-px tiles); LDS = 3 padded input rows = 43,776 B -> 3 blocks/CU =
// 21 waves/CU (66% cap, 4x R7's measured 16.5%). 896 blocks ~ 1.17 gens.
// Each wave: 16 px x all 64 o (acc = 4 x f32x4). Staging via global_load_lds
// from pre-swizzled xps into linear LDS (zero VALU/VGPR; wave-uniform LDS
// base + implicit lane*16 scatter, offset must be a literal). A-fragments
// single-buffered per tap from L1/L2-hot wpk; TLP (5+ waves/SIMD) hides the
// latency. Taps = pure LDS address shifts + verified XOR read swizzle.
// __launch_bounds__(448,5) caps VGPR ~102 (no spill, no over-hoist).
// XCD pin: b = blk & 7.
// -----------------------------------------------------------------------------
__global__ __launch_bounds__(448, 5) void conv16(const unsigned short* __restrict__ xps,
                                                 const unsigned short* __restrict__ wpk,
                                                 const int* __restrict__ mask_idx,
                                                 float* __restrict__ out) {
    __shared__ char xs[3 * WP * Cn * 2];   // 43776 B: 2736 16B chunks, linear

    int b   = blockIdx.x & 7;               // image -> XCD pin
    int row = blockIdx.x >> 3;              // output row 0..111
    int tid = threadIdx.x;
    int wave = tid >> 6, lane = tid & 63;
    int n = lane & 15, g = lane >> 4;

    int cw = wave * 16 + n;                 // this lane's output col
    int mv = mask_idx[row * Wn + cw];       // mask shared across batch

    // ---- Staging: padded rows row..row+2 are contiguous in xps.
    // global src is per-lane; LDS dest is the wave-uniform base (q - lane),
    // hardware scatters at base + lane*16. offset arg must be literal 0.
    {
        const char* gsrc = (const char*)(xps + ((size_t)(b * HP + row) * WP) * Cn);
#pragma unroll
        for (int i = 0; i < 7; ++i) {
            int q = tid + i * 448;          // chunk index; q - lane is uniform
            if (q < 3 * 8 * WP) {           // 2736 chunks (tail masks lanes)
                __builtin_amdgcn_global_load_lds(
                    (glob_u32*)(gsrc + ((size_t)q << 4)),
                    reinterpret_cast<lds_u32*>(reinterpret_cast<uintptr_t>(
                        xs + ((size_t)(q - lane) << 4))),
                    16, 0, 0);
            }
        }
    }

    const u32x4* wv = reinterpret_cast<const u32x4*>(wpk);
    const u32x4 vzero = {0u, 0u, 0u, 0u};
    f32x4 acc[4] = {};                      // 4 o-frags x 16 px

    __syncthreads();   // vmcnt(0) drain: all staging DMAs landed

#pragma unroll
    for (int p = 0; p < 9; ++p) {
        // A-fragments for this tap: 8 x 16B (of x ki), single-buffered.
        u32x4 av[8];
#pragma unroll
        for (int f = 0; f < 8; ++f) av[f] = wv[(p * 8 + f) * 64 + lane];

        int dh = p / 3, dw = p - dh * 3;
        int wq = cw + dw;                   // padded col 0..113
        int sw = wq & 7;
        u32x4 bv[2];
#pragma unroll
        for (int kc = 0; kc < 2; ++kc) {
            int chunk = (dh * WP + wq) * 8 + ((kc * 4 + g) ^ sw);
            bv[kc] = *reinterpret_cast<const u32x4*>(xs + ((size_t)chunk << 4));
        }
        if (mv == p) { bv[0] = vzero; bv[1] = vzero; }

#pragma unroll
        for (int of = 0; of < 4; ++of) {
#pragma unroll
            for (int kc = 0; kc < 2; ++kc) {
                acc[of] = __builtin_amdgcn_mfma_f32_16x16x32_bf16(
                    *reinterpret_cast<bf16x8*>(&av[of * 2 + kc]),
                    *reinterpret_cast<bf16x8*>(&bv[kc]), acc[of], 0, 0, 0);
            }
        }
    }

    // Epilogue: D col = lane&15 (=px), row = (lane>>4)*4 + reg (=o within of).
    float* ob = out + (size_t)(b * On) * Ln + row * Wn + cw;
#pragma unroll
    for (int of = 0; of < 4; ++of) {
#pragma unroll
        for (int reg = 0; reg < 4; ++reg) {
            int o = of * 16 + g * 4 + reg;
            ob[(size_t)o * Ln] = acc[of][reg];
        }
    }
}

// -----------------------------------------------------------------------------
extern "C" void kernel_launch(void* const* d_in, const int* in_sizes, int n_in,
                              void* d_out, int out_size, void* d_ws, size_t ws_size,
                              hipStream_t stream) {
    const float* x    = (const float*)d_in[0];
    const float* w    = (const float*)d_in[1];
    const int*   mask = (const int*)d_in[2];
    float* out = (float*)d_out;

    unsigned short* xps = (unsigned short*)d_ws;                     // 13,307,904 B
    unsigned short* wpk = (unsigned short*)((char*)d_ws + 13307904); // +73,728 B

    prep_kernel<<<948,      128, 0, stream>>>(x, w, xps, wpk);
    conv16     <<<Bn * Hn,  448, 0, stream>>>(xps, wpk, mask, out);
}